// Round 1
// baseline (698.235 us; speedup 1.0000x reference)
//
#include <hip/hip_runtime.h>
#include <hip/hip_bf16.h>

// Problem: B=2048 batch, N=512 clusters, D=C*T=8192 features.
// Phase 1: row norms of y (2048) and m (512).
// Phase 2: dot GEMM [2048x512] + epilogue d2 = (yy+mm) - 2*dot  (scratch in d_out m-region).
// Phase 3: argmin per row (first-index tie-break) -> assign (float) in its final slot.
// Phase 4: per-cluster sequential EMA replay -> final m, sd, p.

#define Bb   2048
#define Nn   512
#define Dd   8192

// ---------------- Phase 1: row norms ----------------
__global__ __launch_bounds__(256) void row_norms(const float* __restrict__ Y,
                                                 const float* __restrict__ M,
                                                 float* __restrict__ yy,
                                                 float* __restrict__ mm) {
    int b = blockIdx.x;
    const float* src;
    float* dst;
    if (b < Bb) { src = Y + (size_t)b * Dd; dst = yy + b; }
    else        { src = M + (size_t)(b - Bb) * Dd; dst = mm + (b - Bb); }
    int t = threadIdx.x;
    float s = 0.f;
#pragma unroll
    for (int u = 0; u < 8; u++) {
        float4 v = *(const float4*)(src + 4 * (t + 256 * u));
        s += v.x * v.x + v.y * v.y + v.z * v.z + v.w * v.w;
    }
    __shared__ float red[256];
    red[t] = s;
    __syncthreads();
    for (int off = 128; off > 0; off >>= 1) {
        if (t < off) red[t] += red[t + off];
        __syncthreads();
    }
    if (t == 0) *dst = red[0];
}

// ---------------- Phase 2: SGEMM d2 ----------------
// grid (8, 32): blockIdx.x = n-tile (64 cols), blockIdx.y = b-tile (64 rows).
// 256 threads, 4x4 micro-tile: rows ty+16i, cols tx+16j (strided to keep
// ds_read_b128 bank conflicts <=2-way at LDS row stride 36 floats).
__global__ __launch_bounds__(256) void gemm_d2(const float* __restrict__ Y,
                                               const float* __restrict__ M,
                                               const float* __restrict__ yy,
                                               const float* __restrict__ mm,
                                               float* __restrict__ D2) {
    __shared__ float As[64][36];
    __shared__ float Bs[64][36];
    int t  = threadIdx.x;
    int tx = t & 15, ty = t >> 4;
    int bn = blockIdx.x, bm = blockIdx.y;
    const float* Yb = Y + (size_t)(bm * 64) * Dd;
    const float* Mb = M + (size_t)(bn * 64) * Dd;
    int ra = t >> 2;            // 0..63, one staging row per thread
    int ca = (t & 3) * 4;       // 0,4,8,12

    float4 a0 = *(const float4*)(Yb + (size_t)ra * Dd + ca);
    float4 a1 = *(const float4*)(Yb + (size_t)ra * Dd + ca + 16);
    float4 b0 = *(const float4*)(Mb + (size_t)ra * Dd + ca);
    float4 b1 = *(const float4*)(Mb + (size_t)ra * Dd + ca + 16);

    float acc[4][4] = {};

    for (int k0 = 0; k0 < Dd; k0 += 32) {
        *(float4*)(&As[ra][ca])      = a0;
        *(float4*)(&As[ra][ca + 16]) = a1;
        *(float4*)(&Bs[ra][ca])      = b0;
        *(float4*)(&Bs[ra][ca + 16]) = b1;
        __syncthreads();
        if (k0 + 32 < Dd) {   // register prefetch of next K-tile overlaps compute
            a0 = *(const float4*)(Yb + (size_t)ra * Dd + k0 + 32 + ca);
            a1 = *(const float4*)(Yb + (size_t)ra * Dd + k0 + 32 + ca + 16);
            b0 = *(const float4*)(Mb + (size_t)ra * Dd + k0 + 32 + ca);
            b1 = *(const float4*)(Mb + (size_t)ra * Dd + k0 + 32 + ca + 16);
        }
#pragma unroll
        for (int kk = 0; kk < 32; kk += 4) {
            float4 a[4], b[4];
#pragma unroll
            for (int i = 0; i < 4; i++) a[i] = *(const float4*)(&As[ty + 16 * i][kk]);
#pragma unroll
            for (int j = 0; j < 4; j++) b[j] = *(const float4*)(&Bs[tx + 16 * j][kk]);
#pragma unroll
            for (int i = 0; i < 4; i++)
#pragma unroll
                for (int j = 0; j < 4; j++) {
                    acc[i][j] += a[i].x * b[j].x;
                    acc[i][j] += a[i].y * b[j].y;
                    acc[i][j] += a[i].z * b[j].z;
                    acc[i][j] += a[i].w * b[j].w;
                }
        }
        __syncthreads();
    }

    int row0 = bm * 64 + ty, col0 = bn * 64 + tx;
#pragma unroll
    for (int i = 0; i < 4; i++) {
        int r = row0 + 16 * i;
        float yyv = yy[r];
#pragma unroll
        for (int j = 0; j < 4; j++) {
            int c = col0 + 16 * j;
            // same expression order as reference: (yy + mm) - 2*dot
            D2[(size_t)r * Nn + c] = (yyv + mm[c]) - 2.0f * acc[i][j];
        }
    }
}

// ---------------- Phase 3: argmin per row ----------------
__global__ __launch_bounds__(64) void argmin_rows(const float* __restrict__ D2,
                                                  float* __restrict__ assignF) {
    int b = blockIdx.x;
    int lane = threadIdx.x;
    float best = 3.4e38f;
    int bi = 0;
#pragma unroll
    for (int j = 0; j < 8; j++) {
        int n = lane + 64 * j;      // ascending within lane -> strict < keeps first
        float v = D2[(size_t)b * Nn + n];
        if (v < best) { best = v; bi = n; }
    }
#pragma unroll
    for (int off = 32; off > 0; off >>= 1) {
        float vo = __shfl_down(best, off);
        int   io = __shfl_down(bi, off);
        if (vo < best || (vo == best && io < bi)) { best = vo; bi = io; }
    }
    if (lane == 0) assignF[b] = (float)bi;
}

// ---------------- Phase 4: per-cluster sequential EMA replay ----------------
__global__ __launch_bounds__(256) void ema_scatter(const float* __restrict__ Y,
                                                   const float* __restrict__ M0,
                                                   const float* __restrict__ SD0,
                                                   const float* __restrict__ P0,
                                                   const float* __restrict__ assignF,
                                                   float* __restrict__ m_out,
                                                   float* __restrict__ sd_out,
                                                   float* __restrict__ p_out) {
    __shared__ int zi[Bb];
    int t = threadIdx.x, n = blockIdx.x;
#pragma unroll
    for (int u = 0; u < 8; u++) zi[t + 256 * u] = (int)assignF[t + 256 * u];
    __syncthreads();

    float4 mc[8], sc[8];
    const float4* m0 = (const float4*)(M0 + (size_t)n * Dd);
    const float4* s0 = (const float4*)(SD0 + (size_t)n * Dd);
#pragma unroll
    for (int u = 0; u < 8; u++) { mc[u] = m0[t + 256 * u]; sc[u] = s0[t + 256 * u]; }

    int cnt = 0;
    for (int i = 0; i < Bb; i++) {
        if (zi[i] == n) {           // block-uniform branch
            cnt++;
            const float4* yr = (const float4*)(Y + (size_t)i * Dd);
#pragma unroll
            for (int u = 0; u < 8; u++) {
                float4 yv = yr[t + 256 * u];
#define EMA_STEP(c)                                                   \
                {                                                     \
                    mc[u].c = mc[u].c * 0.001f + yv.c * 0.999f;       \
                    float d_ = mc[u].c - yv.c;                        \
                    sc[u].c = d_ * d_ * 0.001f + sc[u].c * 0.999f;    \
                }
                EMA_STEP(x) EMA_STEP(y) EMA_STEP(z) EMA_STEP(w)
#undef EMA_STEP
            }
        }
    }

    float4* mo = (float4*)(m_out + (size_t)n * Dd);
    float4* so = (float4*)(sd_out + (size_t)n * Dd);
#pragma unroll
    for (int u = 0; u < 8; u++) { mo[t + 256 * u] = mc[u]; so[t + 256 * u] = sc[u]; }
    if (t == 0) p_out[n] = P0[n] + (float)cnt;
}

extern "C" void kernel_launch(void* const* d_in, const int* in_sizes, int n_in,
                              void* d_out, int out_size, void* d_ws, size_t ws_size,
                              hipStream_t stream) {
    const float* y  = (const float*)d_in[0];
    const float* m  = (const float*)d_in[1];
    const float* sd = (const float*)d_in[2];
    const float* p  = (const float*)d_in[3];

    float* out     = (float*)d_out;
    float* m_out   = out;                       // [512*8192]
    float* sd_out  = out + 4194304;             // [512*8192]
    float* p_out   = out + 8388608;             // [512]
    float* assignF = out + 8389120;             // [2048]

    // Scratch carved out of d_out (consumed before final writes land):
    float* d2 = m_out;        // 2048*512 floats = 4 MB, fits in m region
    float* yy = sd_out;       // 2048 floats at head of sd region
    float* mm = sd_out + Bb;  // 512 floats after yy

    row_norms  <<<Bb + Nn, 256, 0, stream>>>(y, m, yy, mm);
    gemm_d2    <<<dim3(Nn / 64, Bb / 64), 256, 0, stream>>>(y, m, yy, mm, d2);
    argmin_rows<<<Bb, 64, 0, stream>>>(d2, assignF);
    ema_scatter<<<Nn, 256, 0, stream>>>(y, m, sd, p, assignF, m_out, sd_out, p_out);
}

// Round 3
// 494.660 us; speedup vs baseline: 1.4115x; 1.4115x over previous
//
#include <hip/hip_runtime.h>
#include <hip/hip_bf16.h>

// B=2048, N=512, D=8192.
// Pipeline (no d_ws use; scratch carved from d_out with per-block ownership):
//   1. m_norms:    mm[n] = ||m_n||^2            -> p-slot (dead after rescore)
//   2. gemm_coarse: bf16 MFMA dot partials (splitK=4) -> m-region (16 MB, dead after rescore)
//   3. rescore:    coarse argmin + exact f32 rescore of candidates within MARGIN
//                  -> assign (final slot). yy omitted (row-constant in argmin).
//   4. build_lists: per-cluster ordered item lists -> head of each m-row (int),
//                  counts -> p-slot (int). Block n of ema owns row n: no hazard.
//   5. ema_scatter: sequential EMA replay per cluster over its own items only.
// Round-3 fix: CAP 128 -> 2048 (max real cluster count ~139 overflowed the list,
// p was off by exactly 139-128=11). List load in ema_scatter now loops.

#define Bb 2048
#define Nn 512
#define Dd 8192
#define MARGIN 12.0f
#define CAP 2048

typedef __attribute__((ext_vector_type(4))) float f32x4;
typedef __attribute__((ext_vector_type(8))) short s16x8;

union Frag { unsigned u[4]; s16x8 s; };

// pack two f32 into two bf16 (truncation): low16 = hi-bits of `lo`, high16 = hi-bits of `hi`
__device__ inline unsigned pack2(float lo, float hi) {
    return __builtin_amdgcn_perm(__float_as_uint(hi), __float_as_uint(lo), 0x07060302u);
}

// ---------------- 1: m row norms ----------------
__global__ __launch_bounds__(256) void m_norms(const float* __restrict__ M,
                                               float* __restrict__ mm) {
    int n = blockIdx.x, t = threadIdx.x;
    const float4* r = (const float4*)(M + (size_t)n * Dd);
    float s = 0.f;
#pragma unroll
    for (int u = 0; u < 8; u++) {
        float4 v = r[t + 256 * u];
        s += v.x * v.x + v.y * v.y + v.z * v.z + v.w * v.w;
    }
    __shared__ float red[256];
    red[t] = s;
    __syncthreads();
    for (int off = 128; off > 0; off >>= 1) {
        if (t < off) red[t] += red[t + off];
        __syncthreads();
    }
    if (t == 0) mm[n] = red[0];
}

// ---------------- 2: coarse bf16 MFMA GEMM (dot only), splitK=4 ----------------
// grid (4 coltiles, 16 rowtiles, 4 kchunks) = 256 blocks, 256 threads (4 waves).
// Tile 128x128, K-chunk 2048 (64 steps of 32). f32 staged to LDS via
// global_load_lds with XOR seg-swizzle; converted to bf16 at fragment read.
__global__ __launch_bounds__(256) void gemm_coarse(const float* __restrict__ Y,
                                                   const float* __restrict__ M,
                                                   float* __restrict__ part) {
    __shared__ __align__(16) float As[128 * 32];  // [row][seg(8) * 4f32], seg swizzled by row&7
    __shared__ __align__(16) float Bs[128 * 32];
    const int t = threadIdx.x;
    const int lane = t & 63;
    const int w = t >> 6;
    const int ct = blockIdx.x, rt = blockIdx.y, kc = blockIdx.z;

    const size_t ybase = (size_t)rt * 128 * Dd + (size_t)kc * 2048;
    const size_t mbase = (size_t)ct * 128 * Dd + (size_t)kc * 2048;

    // staging map: instr u of wave w covers flat = (w*4+u)*64 + lane
    int rowS[4], soff[4];
#pragma unroll
    for (int u = 0; u < 4; u++) {
        int flat = (w * 4 + u) * 64 + lane;
        int row = flat >> 3, seg = flat & 7;
        rowS[u] = row;
        soff[u] = (seg ^ (row & 7)) * 4;   // swizzled source seg (floats)
    }

    const int wr0 = (w & 1) * 64, wc0 = (w >> 1) * 64;
    const int l15 = lane & 15, quad = lane >> 4;

    f32x4 acc[4][4];
#pragma unroll
    for (int i = 0; i < 4; i++)
#pragma unroll
        for (int j = 0; j < 4; j++) acc[i][j] = (f32x4)(0.0f);

    for (int step = 0; step < 64; step++) {
        const int kpos = step * 32;
#pragma unroll
        for (int u = 0; u < 4; u++) {
            const float* gA = Y + ybase + (size_t)rowS[u] * Dd + kpos + soff[u];
            const float* gB = M + mbase + (size_t)rowS[u] * Dd + kpos + soff[u];
            __builtin_amdgcn_global_load_lds(
                (const __attribute__((address_space(1))) void*)gA,
                (__attribute__((address_space(3))) void*)(As + (w * 4 + u) * 256), 16, 0, 0);
            __builtin_amdgcn_global_load_lds(
                (const __attribute__((address_space(1))) void*)gB,
                (__attribute__((address_space(3))) void*)(Bs + (w * 4 + u) * 256), 16, 0, 0);
        }
        __syncthreads();

        Frag fa[4], fb[4];
#pragma unroll
        for (int ta = 0; ta < 4; ta++) {
            int rowa = wr0 + ta * 16 + l15;
            const float* Ar = As + rowa * 32;
            int s0 = ((quad * 2) ^ (rowa & 7)) * 4;
            int s1 = ((quad * 2 + 1) ^ (rowa & 7)) * 4;
            f32x4 x0 = *(const f32x4*)(Ar + s0);
            f32x4 x1 = *(const f32x4*)(Ar + s1);
            fa[ta].u[0] = pack2(x0[0], x0[1]);
            fa[ta].u[1] = pack2(x0[2], x0[3]);
            fa[ta].u[2] = pack2(x1[0], x1[1]);
            fa[ta].u[3] = pack2(x1[2], x1[3]);
        }
#pragma unroll
        for (int tb = 0; tb < 4; tb++) {
            int rowb = wc0 + tb * 16 + l15;
            const float* Br = Bs + rowb * 32;
            int s0 = ((quad * 2) ^ (rowb & 7)) * 4;
            int s1 = ((quad * 2 + 1) ^ (rowb & 7)) * 4;
            f32x4 x0 = *(const f32x4*)(Br + s0);
            f32x4 x1 = *(const f32x4*)(Br + s1);
            fb[tb].u[0] = pack2(x0[0], x0[1]);
            fb[tb].u[1] = pack2(x0[2], x0[3]);
            fb[tb].u[2] = pack2(x1[0], x1[1]);
            fb[tb].u[3] = pack2(x1[2], x1[3]);
        }
#pragma unroll
        for (int i = 0; i < 4; i++)
#pragma unroll
            for (int j = 0; j < 4; j++)
                acc[i][j] = __builtin_amdgcn_mfma_f32_16x16x32_bf16(fa[i].s, fb[j].s, acc[i][j], 0, 0, 0);
        __syncthreads();
    }

    // store partial dot sums; C/D layout: col = lane&15, row = quad*4 + reg
    float* P = part + (size_t)kc * 1048576;
#pragma unroll
    for (int i = 0; i < 4; i++) {
        int rg = rt * 128 + wr0 + i * 16 + quad * 4;
#pragma unroll
        for (int j = 0; j < 4; j++) {
            int cg = ct * 128 + wc0 + j * 16 + l15;
#pragma unroll
            for (int r = 0; r < 4; r++)
                P[(size_t)(rg + r) * Nn + cg] = acc[i][j][r];
        }
    }
}

// ---------------- 3: coarse argmin + exact rescore ----------------
__global__ __launch_bounds__(256) void rescore(const float* __restrict__ Y,
                                               const float* __restrict__ M,
                                               const float* __restrict__ part,
                                               const float* __restrict__ mm,
                                               float* __restrict__ assignF) {
    __shared__ __align__(16) float ys[Dd];   // 32 KB
    __shared__ float d2row[Nn];
    __shared__ float red[256];
    int b = blockIdx.x, t = threadIdx.x;

    const float4* yrow = (const float4*)(Y + (size_t)b * Dd);
    float4* ys4 = (float4*)ys;
#pragma unroll
    for (int u = 0; u < 8; u++) ys4[t + 256 * u] = yrow[t + 256 * u];

#pragma unroll
    for (int cc = 0; cc < 2; cc++) {
        int c = t + cc * 256;
        float dot = 0.f;
#pragma unroll
        for (int k = 0; k < 4; k++) dot += part[(size_t)k * 1048576 + (size_t)b * Nn + c];
        d2row[c] = mm[c] - 2.0f * dot;
    }
    __syncthreads();

    float mn = fminf(d2row[t], d2row[t + 256]);
    red[t] = mn;
    __syncthreads();
    for (int off = 128; off > 0; off >>= 1) {
        if (t < off) red[t] = fminf(red[t], red[t + off]);
        __syncthreads();
    }
    float thresh = red[0] + MARGIN;
    __syncthreads();

    float bestV = 3.4e38f;
    int bestI = 0;
    for (int c = 0; c < Nn; c++) {
        if (d2row[c] <= thresh) {          // block-uniform branch
            const float4* mrow = (const float4*)(M + (size_t)c * Dd);
            float p = 0.f;
#pragma unroll
            for (int u = 0; u < 8; u++) {
                float4 mv = mrow[t + 256 * u];
                float4 yv = ys4[t + 256 * u];
                p += mv.x * yv.x + mv.y * yv.y + mv.z * yv.z + mv.w * yv.w;
            }
            red[t] = p;
            __syncthreads();
            for (int off = 128; off > 0; off >>= 1) {
                if (t < off) red[t] += red[t + off];
                __syncthreads();
            }
            float d2e = mm[c] - 2.0f * red[0];
            if (d2e < bestV) { bestV = d2e; bestI = c; }   // strict <: lowest index wins
            __syncthreads();
        }
    }
    if (t == 0) assignF[b] = (float)bestI;
}

// ---------------- 4: build ordered per-cluster item lists ----------------
__global__ __launch_bounds__(512) void build_lists(const float* __restrict__ assignF,
                                                   float* m_out, float* p_out) {
    __shared__ int zi[Bb];
    int t = threadIdx.x;
#pragma unroll
    for (int u = 0; u < 4; u++) zi[t + 512 * u] = (int)assignF[t + 512 * u];
    __syncthreads();
    int cnt = 0;
    int* lst = (int*)(m_out + (size_t)t * Dd);   // head of this cluster's own m-row
    for (int i = 0; i < Bb; i++) {
        if (zi[i] == t) {
            if (cnt < CAP) lst[cnt] = i;
            cnt++;
        }
    }
    ((int*)p_out)[t] = cnt < CAP ? cnt : CAP;
}

// ---------------- 5: per-cluster sequential EMA over its own items ----------------
__global__ __launch_bounds__(256) void ema_scatter(const float* __restrict__ Y,
                                                   const float* __restrict__ M0,
                                                   const float* __restrict__ SD0,
                                                   const float* __restrict__ P0,
                                                   float* m_out, float* sd_out, float* p_out) {
    __shared__ int lst[CAP];
    __shared__ int cntSh;
    int t = threadIdx.x, n = blockIdx.x;
    if (t == 0) cntSh = ((const int*)p_out)[n];
    __syncthreads();
    int cnt = cntSh;
    for (int u = t; u < cnt; u += 256)
        lst[u] = ((const int*)(m_out + (size_t)n * Dd))[u];
    __syncthreads();

    float4 mc[8], sc[8];
    const float4* m0 = (const float4*)(M0 + (size_t)n * Dd);
    const float4* s0 = (const float4*)(SD0 + (size_t)n * Dd);
#pragma unroll
    for (int u = 0; u < 8; u++) { mc[u] = m0[t + 256 * u]; sc[u] = s0[t + 256 * u]; }

    for (int j = 0; j < cnt; j++) {
        const float4* yr = (const float4*)(Y + (size_t)lst[j] * Dd);
#pragma unroll
        for (int u = 0; u < 8; u++) {
            float4 yv = yr[t + 256 * u];
#define EMA_STEP(c)                                               \
            {                                                     \
                mc[u].c = mc[u].c * 0.001f + yv.c * 0.999f;       \
                float d_ = mc[u].c - yv.c;                        \
                sc[u].c = d_ * d_ * 0.001f + sc[u].c * 0.999f;    \
            }
            EMA_STEP(x) EMA_STEP(y) EMA_STEP(z) EMA_STEP(w)
#undef EMA_STEP
        }
    }

    float4* mo = (float4*)(m_out + (size_t)n * Dd);
    float4* so = (float4*)(sd_out + (size_t)n * Dd);
#pragma unroll
    for (int u = 0; u < 8; u++) { mo[t + 256 * u] = mc[u]; so[t + 256 * u] = sc[u]; }
    if (t == 0) p_out[n] = P0[n] + (float)cnt;
}

extern "C" void kernel_launch(void* const* d_in, const int* in_sizes, int n_in,
                              void* d_out, int out_size, void* d_ws, size_t ws_size,
                              hipStream_t stream) {
    const float* y  = (const float*)d_in[0];
    const float* m  = (const float*)d_in[1];
    const float* sd = (const float*)d_in[2];
    const float* p  = (const float*)d_in[3];

    float* out     = (float*)d_out;
    float* m_out   = out;                       // also: GEMM partials (16 MB), list heads
    float* sd_out  = out + 4194304;
    float* p_out   = out + 8388608;             // also: mm norms, then counts
    float* assignF = out + 8389120;

    m_norms    <<<Nn, 256, 0, stream>>>(m, p_out);
    gemm_coarse<<<dim3(4, 16, 4), 256, 0, stream>>>(y, m, m_out);
    rescore    <<<Bb, 256, 0, stream>>>(y, m, m_out, p_out, assignF);
    build_lists<<<1, 512, 0, stream>>>(assignF, m_out, p_out);
    ema_scatter<<<Nn, 256, 0, stream>>>(y, m, sd, p, m_out, sd_out, p_out);
}

// Round 4
// 318.242 us; speedup vs baseline: 2.1940x; 1.5544x over previous
//
#include <hip/hip_runtime.h>
#include <hip/hip_bf16.h>

// B=2048, N=512, D=8192.
// Pipeline (no d_ws use; scratch carved from d_out with per-block ownership):
//   1. m_norms:    mm[n] = ||m_n||^2            -> p-slot (dead after rescore)
//   2. gemm_coarse: bf16 MFMA dot partials (splitK=4) -> m-region (16 MB, dead after rescore)
//   3. rescore:    coarse argmin + exact f32 rescore of candidates within MARGIN
//                  -> assign (final slot). yy omitted (row-constant in argmin).
//   4. build_lists: per-cluster ordered item lists -> head of each m-row (int),
//                  counts -> p-slot (int). Block n of ema owns row n: no hazard.
//   5. ema_scatter: sequential EMA replay per cluster over its own items only.
// Round-4: build_lists 1-block serial LDS-latency chain (118.7 us measured, ~139
// cyc/iter = ds_read latency) -> 512-block wave-ballot version. rescore's
// 512-iter serial threshold scan -> LDS-atomic candidate list (~1-3 entries).

#define Bb 2048
#define Nn 512
#define Dd 8192
#define MARGIN 12.0f

typedef __attribute__((ext_vector_type(4))) float f32x4;
typedef __attribute__((ext_vector_type(8))) short s16x8;

union Frag { unsigned u[4]; s16x8 s; };

// pack two f32 into two bf16 (truncation): low16 = hi-bits of `lo`, high16 = hi-bits of `hi`
__device__ inline unsigned pack2(float lo, float hi) {
    return __builtin_amdgcn_perm(__float_as_uint(hi), __float_as_uint(lo), 0x07060302u);
}

// ---------------- 1: m row norms ----------------
__global__ __launch_bounds__(256) void m_norms(const float* __restrict__ M,
                                               float* __restrict__ mm) {
    int n = blockIdx.x, t = threadIdx.x;
    const float4* r = (const float4*)(M + (size_t)n * Dd);
    float s = 0.f;
#pragma unroll
    for (int u = 0; u < 8; u++) {
        float4 v = r[t + 256 * u];
        s += v.x * v.x + v.y * v.y + v.z * v.z + v.w * v.w;
    }
    __shared__ float red[256];
    red[t] = s;
    __syncthreads();
    for (int off = 128; off > 0; off >>= 1) {
        if (t < off) red[t] += red[t + off];
        __syncthreads();
    }
    if (t == 0) mm[n] = red[0];
}

// ---------------- 2: coarse bf16 MFMA GEMM (dot only), splitK=4 ----------------
// grid (4 coltiles, 16 rowtiles, 4 kchunks) = 256 blocks, 256 threads (4 waves).
// Tile 128x128, K-chunk 2048 (64 steps of 32). f32 staged to LDS via
// global_load_lds with XOR seg-swizzle; converted to bf16 at fragment read.
__global__ __launch_bounds__(256) void gemm_coarse(const float* __restrict__ Y,
                                                   const float* __restrict__ M,
                                                   float* __restrict__ part) {
    __shared__ __align__(16) float As[128 * 32];  // [row][seg(8) * 4f32], seg swizzled by row&7
    __shared__ __align__(16) float Bs[128 * 32];
    const int t = threadIdx.x;
    const int lane = t & 63;
    const int w = t >> 6;
    const int ct = blockIdx.x, rt = blockIdx.y, kc = blockIdx.z;

    const size_t ybase = (size_t)rt * 128 * Dd + (size_t)kc * 2048;
    const size_t mbase = (size_t)ct * 128 * Dd + (size_t)kc * 2048;

    // staging map: instr u of wave w covers flat = (w*4+u)*64 + lane
    int rowS[4], soff[4];
#pragma unroll
    for (int u = 0; u < 4; u++) {
        int flat = (w * 4 + u) * 64 + lane;
        int row = flat >> 3, seg = flat & 7;
        rowS[u] = row;
        soff[u] = (seg ^ (row & 7)) * 4;   // swizzled source seg (floats)
    }

    const int wr0 = (w & 1) * 64, wc0 = (w >> 1) * 64;
    const int l15 = lane & 15, quad = lane >> 4;

    f32x4 acc[4][4];
#pragma unroll
    for (int i = 0; i < 4; i++)
#pragma unroll
        for (int j = 0; j < 4; j++) acc[i][j] = (f32x4)(0.0f);

    for (int step = 0; step < 64; step++) {
        const int kpos = step * 32;
#pragma unroll
        for (int u = 0; u < 4; u++) {
            const float* gA = Y + ybase + (size_t)rowS[u] * Dd + kpos + soff[u];
            const float* gB = M + mbase + (size_t)rowS[u] * Dd + kpos + soff[u];
            __builtin_amdgcn_global_load_lds(
                (const __attribute__((address_space(1))) void*)gA,
                (__attribute__((address_space(3))) void*)(As + (w * 4 + u) * 256), 16, 0, 0);
            __builtin_amdgcn_global_load_lds(
                (const __attribute__((address_space(1))) void*)gB,
                (__attribute__((address_space(3))) void*)(Bs + (w * 4 + u) * 256), 16, 0, 0);
        }
        __syncthreads();

        Frag fa[4], fb[4];
#pragma unroll
        for (int ta = 0; ta < 4; ta++) {
            int rowa = wr0 + ta * 16 + l15;
            const float* Ar = As + rowa * 32;
            int s0 = ((quad * 2) ^ (rowa & 7)) * 4;
            int s1 = ((quad * 2 + 1) ^ (rowa & 7)) * 4;
            f32x4 x0 = *(const f32x4*)(Ar + s0);
            f32x4 x1 = *(const f32x4*)(Ar + s1);
            fa[ta].u[0] = pack2(x0[0], x0[1]);
            fa[ta].u[1] = pack2(x0[2], x0[3]);
            fa[ta].u[2] = pack2(x1[0], x1[1]);
            fa[ta].u[3] = pack2(x1[2], x1[3]);
        }
#pragma unroll
        for (int tb = 0; tb < 4; tb++) {
            int rowb = wc0 + tb * 16 + l15;
            const float* Br = Bs + rowb * 32;
            int s0 = ((quad * 2) ^ (rowb & 7)) * 4;
            int s1 = ((quad * 2 + 1) ^ (rowb & 7)) * 4;
            f32x4 x0 = *(const f32x4*)(Br + s0);
            f32x4 x1 = *(const f32x4*)(Br + s1);
            fb[tb].u[0] = pack2(x0[0], x0[1]);
            fb[tb].u[1] = pack2(x0[2], x0[3]);
            fb[tb].u[2] = pack2(x1[0], x1[1]);
            fb[tb].u[3] = pack2(x1[2], x1[3]);
        }
#pragma unroll
        for (int i = 0; i < 4; i++)
#pragma unroll
            for (int j = 0; j < 4; j++)
                acc[i][j] = __builtin_amdgcn_mfma_f32_16x16x32_bf16(fa[i].s, fb[j].s, acc[i][j], 0, 0, 0);
        __syncthreads();
    }

    // store partial dot sums; C/D layout: col = lane&15, row = quad*4 + reg
    float* P = part + (size_t)kc * 1048576;
#pragma unroll
    for (int i = 0; i < 4; i++) {
        int rg = rt * 128 + wr0 + i * 16 + quad * 4;
#pragma unroll
        for (int j = 0; j < 4; j++) {
            int cg = ct * 128 + wc0 + j * 16 + l15;
#pragma unroll
            for (int r = 0; r < 4; r++)
                P[(size_t)(rg + r) * Nn + cg] = acc[i][j][r];
        }
    }
}

// ---------------- 3: coarse argmin + exact rescore (candidate list) ----------------
__global__ __launch_bounds__(256) void rescore(const float* __restrict__ Y,
                                               const float* __restrict__ M,
                                               const float* __restrict__ part,
                                               const float* __restrict__ mm,
                                               float* __restrict__ assignF) {
    __shared__ __align__(16) float ys[Dd];   // 32 KB
    __shared__ float d2row[Nn];
    __shared__ float red[256];
    __shared__ int candList[Nn];
    __shared__ int candCnt;
    int b = blockIdx.x, t = threadIdx.x;
    if (t == 0) candCnt = 0;

    const float4* yrow = (const float4*)(Y + (size_t)b * Dd);
    float4* ys4 = (float4*)ys;
#pragma unroll
    for (int u = 0; u < 8; u++) ys4[t + 256 * u] = yrow[t + 256 * u];

#pragma unroll
    for (int cc = 0; cc < 2; cc++) {
        int c = t + cc * 256;
        float dot = 0.f;
#pragma unroll
        for (int k = 0; k < 4; k++) dot += part[(size_t)k * 1048576 + (size_t)b * Nn + c];
        d2row[c] = mm[c] - 2.0f * dot;
    }
    __syncthreads();

    float mn = fminf(d2row[t], d2row[t + 256]);
    red[t] = mn;
    __syncthreads();
    for (int off = 128; off > 0; off >>= 1) {
        if (t < off) red[t] = fminf(red[t], red[t + off]);
        __syncthreads();
    }
    float thresh = red[0] + MARGIN;
    __syncthreads();

    // parallel candidate-list build (order irrelevant; tie-break handled below)
#pragma unroll
    for (int cc = 0; cc < 2; cc++) {
        int c = t + cc * 256;
        if (d2row[c] <= thresh) candList[atomicAdd(&candCnt, 1)] = c;
    }
    __syncthreads();
    int ncand = candCnt;

    float bestV = 3.4e38f;
    int bestI = 0x3fffffff;
    for (int j = 0; j < ncand; j++) {
        int c = candList[j];
        const float4* mrow = (const float4*)(M + (size_t)c * Dd);
        float p = 0.f;
#pragma unroll
        for (int u = 0; u < 8; u++) {
            float4 mv = mrow[t + 256 * u];
            float4 yv = ys4[t + 256 * u];
            p += mv.x * yv.x + mv.y * yv.y + mv.z * yv.z + mv.w * yv.w;
        }
        red[t] = p;
        __syncthreads();
        for (int off = 128; off > 0; off >>= 1) {
            if (t < off) red[t] += red[t + off];
            __syncthreads();
        }
        float d2e = mm[c] - 2.0f * red[0];
        if (d2e < bestV || (d2e == bestV && c < bestI)) { bestV = d2e; bestI = c; }
        __syncthreads();
    }
    if (t == 0) assignF[b] = (float)bestI;
}

// ---------------- 4: per-cluster ordered item lists (wave ballot) ----------------
__global__ __launch_bounds__(64) void build_lists(const float* __restrict__ assignF,
                                                  float* m_out, float* p_out) {
    int n = blockIdx.x, lane = threadIdx.x;
    int z[32];
#pragma unroll
    for (int u = 0; u < 32; u++) z[u] = (int)assignF[u * 64 + lane];
    int* lst = (int*)(m_out + (size_t)n * Dd);   // head of this cluster's own m-row
    int cnt = 0;
#pragma unroll
    for (int u = 0; u < 32; u++) {
        unsigned long long mask = __ballot(z[u] == n);
        if (z[u] == n) {
            int pos = cnt + (int)__popcll(mask & ((1ull << lane) - 1ull));
            lst[pos] = u * 64 + lane;
        }
        cnt += (int)__popcll(mask);
    }
    if (lane == 0) ((int*)p_out)[n] = cnt;
}

// ---------------- 5: per-cluster sequential EMA over its own items ----------------
__global__ __launch_bounds__(256) void ema_scatter(const float* __restrict__ Y,
                                                   const float* __restrict__ M0,
                                                   const float* __restrict__ SD0,
                                                   const float* __restrict__ P0,
                                                   float* m_out, float* sd_out, float* p_out) {
    __shared__ int lst[Bb];
    __shared__ int cntSh;
    int t = threadIdx.x, n = blockIdx.x;
    if (t == 0) cntSh = ((const int*)p_out)[n];
    __syncthreads();
    int cnt = cntSh;
    for (int u = t; u < cnt; u += 256)
        lst[u] = ((const int*)(m_out + (size_t)n * Dd))[u];
    __syncthreads();

    float4 mc[8], sc[8];
    const float4* m0 = (const float4*)(M0 + (size_t)n * Dd);
    const float4* s0 = (const float4*)(SD0 + (size_t)n * Dd);
#pragma unroll
    for (int u = 0; u < 8; u++) { mc[u] = m0[t + 256 * u]; sc[u] = s0[t + 256 * u]; }

    for (int j = 0; j < cnt; j++) {
        const float4* yr = (const float4*)(Y + (size_t)lst[j] * Dd);
#pragma unroll
        for (int u = 0; u < 8; u++) {
            float4 yv = yr[t + 256 * u];
#define EMA_STEP(c)                                               \
            {                                                     \
                mc[u].c = mc[u].c * 0.001f + yv.c * 0.999f;       \
                float d_ = mc[u].c - yv.c;                        \
                sc[u].c = d_ * d_ * 0.001f + sc[u].c * 0.999f;    \
            }
            EMA_STEP(x) EMA_STEP(y) EMA_STEP(z) EMA_STEP(w)
#undef EMA_STEP
        }
    }

    float4* mo = (float4*)(m_out + (size_t)n * Dd);
    float4* so = (float4*)(sd_out + (size_t)n * Dd);
#pragma unroll
    for (int u = 0; u < 8; u++) { mo[t + 256 * u] = mc[u]; so[t + 256 * u] = sc[u]; }
    if (t == 0) p_out[n] = P0[n] + (float)cnt;
}

extern "C" void kernel_launch(void* const* d_in, const int* in_sizes, int n_in,
                              void* d_out, int out_size, void* d_ws, size_t ws_size,
                              hipStream_t stream) {
    const float* y  = (const float*)d_in[0];
    const float* m  = (const float*)d_in[1];
    const float* sd = (const float*)d_in[2];
    const float* p  = (const float*)d_in[3];

    float* out     = (float*)d_out;
    float* m_out   = out;                       // also: GEMM partials (16 MB), list heads
    float* sd_out  = out + 4194304;
    float* p_out   = out + 8388608;             // also: mm norms, then counts
    float* assignF = out + 8389120;

    m_norms    <<<Nn, 256, 0, stream>>>(m, p_out);
    gemm_coarse<<<dim3(4, 16, 4), 256, 0, stream>>>(y, m, m_out);
    rescore    <<<Bb, 256, 0, stream>>>(y, m, m_out, p_out, assignF);
    build_lists<<<Nn, 64, 0, stream>>>(assignF, m_out, p_out);
    ema_scatter<<<Nn, 256, 0, stream>>>(y, m, sd, p, m_out, sd_out, p_out);
}

// Round 5
// 253.030 us; speedup vs baseline: 2.7595x; 1.2577x over previous
//
#include <hip/hip_runtime.h>
#include <hip/hip_bf16.h>

// B=2048, N=512, D=8192.
// Pipeline (no d_ws; scratch carved from d_out with per-block ownership):
//   1. m_norms:     mm[n]=||m_n||^2 -> p-slot (dead after rescore)
//   2. gemm_coarse: bf16 MFMA dot partials, splitK=8 -> m+sd regions (32 MB, dead after rescore)
//   3. rescore:     coarse argmin + margin candidates; exact f32 dots ONLY if >=2
//                   candidates (argmin needs exact values only to compare candidates)
//   4. build_lists: per-cluster ordered item lists, 4 copies (one per D-slice) into
//                   m-row slice heads; counts into sd-row slice heads
//   5. ema_scatter: grid (N,4); block (n,s) owns 2048-float slice s of cluster n,
//                   reads list/cnt from its OWN slice copy before overwriting it.
// Round-5: gemm splitK 4->8 (1->2 blocks/CU; was latency-bound at Occ 10%),
// rescore lean (ncand==1 fast path, shfl reductions), ema D-split x4.

#define Bb 2048
#define Nn 512
#define Dd 8192
#define MARGIN 12.0f
#define KC 8
#define KSTEPS 32   // (Dd/KC)/32

typedef __attribute__((ext_vector_type(4))) float f32x4;
typedef __attribute__((ext_vector_type(8))) short s16x8;

union Frag { unsigned u[4]; s16x8 s; };

__device__ inline unsigned pack2(float lo, float hi) {
    return __builtin_amdgcn_perm(__float_as_uint(hi), __float_as_uint(lo), 0x07060302u);
}

__device__ inline void ema4(float4& mcv, float4& scv, const float4 yv) {
#define EMA_C(c) { mcv.c = mcv.c * 0.001f + yv.c * 0.999f; \
                   float d_ = mcv.c - yv.c;                 \
                   scv.c = d_ * d_ * 0.001f + scv.c * 0.999f; }
    EMA_C(x) EMA_C(y) EMA_C(z) EMA_C(w)
#undef EMA_C
}

// ---------------- 1: m row norms ----------------
__global__ __launch_bounds__(256) void m_norms(const float* __restrict__ M,
                                               float* __restrict__ mm) {
    int n = blockIdx.x, t = threadIdx.x;
    const float4* r = (const float4*)(M + (size_t)n * Dd);
    float s = 0.f;
#pragma unroll
    for (int u = 0; u < 8; u++) {
        float4 v = r[t + 256 * u];
        s += v.x * v.x + v.y * v.y + v.z * v.z + v.w * v.w;
    }
    __shared__ float red[256];
    red[t] = s;
    __syncthreads();
    for (int off = 128; off > 0; off >>= 1) {
        if (t < off) red[t] += red[t + off];
        __syncthreads();
    }
    if (t == 0) mm[n] = red[0];
}

// ---------------- 2: coarse bf16 MFMA GEMM (dot only), splitK=8 ----------------
// grid (4 coltiles, 16 rowtiles, 8 kchunks) = 512 blocks (2/CU), 256 threads.
// Tile 128x128, K-chunk 1024 (32 steps of 32). f32 staged via global_load_lds
// with XOR seg-swizzle; converted to bf16 at fragment read.
__global__ __launch_bounds__(256) void gemm_coarse(const float* __restrict__ Y,
                                                   const float* __restrict__ M,
                                                   float* __restrict__ part) {
    __shared__ __align__(16) float As[128 * 32];
    __shared__ __align__(16) float Bs[128 * 32];
    const int t = threadIdx.x;
    const int lane = t & 63;
    const int w = t >> 6;
    const int ct = blockIdx.x, rt = blockIdx.y, kc = blockIdx.z;

    const size_t ybase = (size_t)rt * 128 * Dd + (size_t)kc * (Dd / KC);
    const size_t mbase = (size_t)ct * 128 * Dd + (size_t)kc * (Dd / KC);

    int rowS[4], soff[4];
#pragma unroll
    for (int u = 0; u < 4; u++) {
        int flat = (w * 4 + u) * 64 + lane;
        int row = flat >> 3, seg = flat & 7;
        rowS[u] = row;
        soff[u] = (seg ^ (row & 7)) * 4;
    }

    const int wr0 = (w & 1) * 64, wc0 = (w >> 1) * 64;
    const int l15 = lane & 15, quad = lane >> 4;

    f32x4 acc[4][4];
#pragma unroll
    for (int i = 0; i < 4; i++)
#pragma unroll
        for (int j = 0; j < 4; j++) acc[i][j] = (f32x4)(0.0f);

    for (int step = 0; step < KSTEPS; step++) {
        const int kpos = step * 32;
#pragma unroll
        for (int u = 0; u < 4; u++) {
            const float* gA = Y + ybase + (size_t)rowS[u] * Dd + kpos + soff[u];
            const float* gB = M + mbase + (size_t)rowS[u] * Dd + kpos + soff[u];
            __builtin_amdgcn_global_load_lds(
                (const __attribute__((address_space(1))) void*)gA,
                (__attribute__((address_space(3))) void*)(As + (w * 4 + u) * 256), 16, 0, 0);
            __builtin_amdgcn_global_load_lds(
                (const __attribute__((address_space(1))) void*)gB,
                (__attribute__((address_space(3))) void*)(Bs + (w * 4 + u) * 256), 16, 0, 0);
        }
        __syncthreads();

        Frag fa[4], fb[4];
#pragma unroll
        for (int ta = 0; ta < 4; ta++) {
            int rowa = wr0 + ta * 16 + l15;
            const float* Ar = As + rowa * 32;
            int s0 = ((quad * 2) ^ (rowa & 7)) * 4;
            int s1 = ((quad * 2 + 1) ^ (rowa & 7)) * 4;
            f32x4 x0 = *(const f32x4*)(Ar + s0);
            f32x4 x1 = *(const f32x4*)(Ar + s1);
            fa[ta].u[0] = pack2(x0[0], x0[1]);
            fa[ta].u[1] = pack2(x0[2], x0[3]);
            fa[ta].u[2] = pack2(x1[0], x1[1]);
            fa[ta].u[3] = pack2(x1[2], x1[3]);
        }
#pragma unroll
        for (int tb = 0; tb < 4; tb++) {
            int rowb = wc0 + tb * 16 + l15;
            const float* Br = Bs + rowb * 32;
            int s0 = ((quad * 2) ^ (rowb & 7)) * 4;
            int s1 = ((quad * 2 + 1) ^ (rowb & 7)) * 4;
            f32x4 x0 = *(const f32x4*)(Br + s0);
            f32x4 x1 = *(const f32x4*)(Br + s1);
            fb[tb].u[0] = pack2(x0[0], x0[1]);
            fb[tb].u[1] = pack2(x0[2], x0[3]);
            fb[tb].u[2] = pack2(x1[0], x1[1]);
            fb[tb].u[3] = pack2(x1[2], x1[3]);
        }
#pragma unroll
        for (int i = 0; i < 4; i++)
#pragma unroll
            for (int j = 0; j < 4; j++)
                acc[i][j] = __builtin_amdgcn_mfma_f32_16x16x32_bf16(fa[i].s, fb[j].s, acc[i][j], 0, 0, 0);
        __syncthreads();
    }

    float* P = part + (size_t)kc * (Bb * Nn);
#pragma unroll
    for (int i = 0; i < 4; i++) {
        int rg = rt * 128 + wr0 + i * 16 + quad * 4;
#pragma unroll
        for (int j = 0; j < 4; j++) {
            int cg = ct * 128 + wc0 + j * 16 + l15;
#pragma unroll
            for (int r = 0; r < 4; r++)
                P[(size_t)(rg + r) * Nn + cg] = acc[i][j][r];
        }
    }
}

// ---------------- 3: coarse argmin + conditional exact rescore ----------------
__global__ __launch_bounds__(256) void rescore(const float* __restrict__ Y,
                                               const float* __restrict__ M,
                                               const float* __restrict__ part,
                                               const float* __restrict__ mm,
                                               float* __restrict__ assignF) {
    __shared__ float redW[4];
    __shared__ int candList[Nn];
    __shared__ int candCnt;
    int b = blockIdx.x, t = threadIdx.x, lane = t & 63, w = t >> 6;
    if (t == 0) candCnt = 0;

    int c0 = t, c1 = t + 256;
    float dot0 = 0.f, dot1 = 0.f;
#pragma unroll
    for (int k = 0; k < KC; k++) {
        dot0 += part[(size_t)k * (Bb * Nn) + (size_t)b * Nn + c0];
        dot1 += part[(size_t)k * (Bb * Nn) + (size_t)b * Nn + c1];
    }
    float d0 = mm[c0] - 2.0f * dot0;
    float d1 = mm[c1] - 2.0f * dot1;

    float mn = fminf(d0, d1);
#pragma unroll
    for (int off = 32; off > 0; off >>= 1) mn = fminf(mn, __shfl_xor(mn, off));
    if (lane == 0) redW[w] = mn;
    __syncthreads();
    float thresh = fminf(fminf(redW[0], redW[1]), fminf(redW[2], redW[3])) + MARGIN;

    if (d0 <= thresh) candList[atomicAdd(&candCnt, 1)] = c0;
    if (d1 <= thresh) candList[atomicAdd(&candCnt, 1)] = c1;
    __syncthreads();
    int ncand = candCnt;

    if (ncand == 1) {                 // uncontested coarse winner: exact dot unnecessary
        if (t == 0) assignF[b] = (float)candList[0];
        return;
    }

    float bestV = 3.4e38f;
    int bestI = 0x3fffffff;
    for (int j = 0; j < ncand; j++) {
        int c = candList[j];
        const float4* yr = (const float4*)(Y + (size_t)b * Dd);
        const float4* mr = (const float4*)(M + (size_t)c * Dd);
        float p = 0.f;
#pragma unroll
        for (int u = 0; u < 8; u++) {
            float4 yv = yr[t + 256 * u];
            float4 mv = mr[t + 256 * u];
            p += yv.x * mv.x + yv.y * mv.y + yv.z * mv.z + yv.w * mv.w;
        }
#pragma unroll
        for (int off = 32; off > 0; off >>= 1) p += __shfl_xor(p, off);
        if (lane == 0) redW[w] = p;
        __syncthreads();
        if (t == 0) {
            float d2e = mm[c] - 2.0f * (redW[0] + redW[1] + redW[2] + redW[3]);
            if (d2e < bestV || (d2e == bestV && c < bestI)) { bestV = d2e; bestI = c; }
        }
        __syncthreads();
    }
    if (t == 0) assignF[b] = (float)bestI;
}

// ---------------- 4: per-cluster ordered lists, 4 slice copies ----------------
__global__ __launch_bounds__(64) void build_lists(const float* __restrict__ assignF,
                                                  float* m_out, float* sd_out) {
    int n = blockIdx.x, lane = threadIdx.x;
    int z[32];
#pragma unroll
    for (int u = 0; u < 32; u++) z[u] = (int)assignF[u * 64 + lane];
    int* lrow = (int*)(m_out + (size_t)n * Dd);
    int cnt = 0;
#pragma unroll
    for (int u = 0; u < 32; u++) {
        unsigned long long mask = __ballot(z[u] == n);
        if (z[u] == n) {
            int pos = cnt + (int)__popcll(mask & ((1ull << lane) - 1ull));
#pragma unroll
            for (int s = 0; s < 4; s++) lrow[s * 2048 + pos] = u * 64 + lane;
        }
        cnt += (int)__popcll(mask);
    }
    if (lane == 0) {
        int* crow = (int*)(sd_out + (size_t)n * Dd);
#pragma unroll
        for (int s = 0; s < 4; s++) crow[s * 2048] = cnt;
    }
}

// ---------------- 5: per-cluster sequential EMA, D-sliced x4 ----------------
__global__ __launch_bounds__(256) void ema_scatter(const float* __restrict__ Y,
                                                   const float* __restrict__ M0,
                                                   const float* __restrict__ SD0,
                                                   const float* __restrict__ P0,
                                                   float* m_out, float* sd_out, float* p_out) {
    __shared__ int lst[Bb];
    __shared__ int cntSh;
    int n = blockIdx.x, s = blockIdx.y, t = threadIdx.x;
    size_t off = (size_t)n * Dd + (size_t)s * 2048;

    if (t == 0) cntSh = ((const int*)(sd_out + off))[0];
    __syncthreads();
    int cnt = cntSh;
    const int* lsrc = (const int*)(m_out + off);
    for (int u = t; u < cnt; u += 256) lst[u] = lsrc[u];
    __syncthreads();

    float4 mc0 = *(const float4*)(M0 + off + 4 * t);
    float4 mc1 = *(const float4*)(M0 + off + 1024 + 4 * t);
    float4 sc0 = *(const float4*)(SD0 + off + 4 * t);
    float4 sc1 = *(const float4*)(SD0 + off + 1024 + 4 * t);

    for (int j = 0; j < cnt; j++) {
        const float* yb = Y + (size_t)lst[j] * Dd + (size_t)s * 2048;
        float4 y0 = *(const float4*)(yb + 4 * t);
        float4 y1 = *(const float4*)(yb + 1024 + 4 * t);
        ema4(mc0, sc0, y0);
        ema4(mc1, sc1, y1);
    }

    *(float4*)(m_out + off + 4 * t) = mc0;
    *(float4*)(m_out + off + 1024 + 4 * t) = mc1;
    *(float4*)(sd_out + off + 4 * t) = sc0;
    *(float4*)(sd_out + off + 1024 + 4 * t) = sc1;
    if (s == 0 && t == 0) p_out[n] = P0[n] + (float)cnt;
}

extern "C" void kernel_launch(void* const* d_in, const int* in_sizes, int n_in,
                              void* d_out, int out_size, void* d_ws, size_t ws_size,
                              hipStream_t stream) {
    const float* y  = (const float*)d_in[0];
    const float* m  = (const float*)d_in[1];
    const float* sd = (const float*)d_in[2];
    const float* p  = (const float*)d_in[3];

    float* out     = (float*)d_out;
    float* m_out   = out;                       // also: partial slices 0-3, list copies
    float* sd_out  = out + 4194304;             // also: partial slices 4-7, count copies
    float* p_out   = out + 8388608;             // also: mm norms
    float* assignF = out + 8389120;

    m_norms    <<<Nn, 256, 0, stream>>>(m, p_out);
    gemm_coarse<<<dim3(4, 16, KC), 256, 0, stream>>>(y, m, m_out);
    rescore    <<<Bb, 256, 0, stream>>>(y, m, m_out, p_out, assignF);
    build_lists<<<Nn, 64, 0, stream>>>(assignF, m_out, sd_out);
    ema_scatter<<<dim3(Nn, 4), 256, 0, stream>>>(y, m, sd, p, m_out, sd_out, p_out);
}

// Round 7
// 252.438 us; speedup vs baseline: 2.7660x; 1.0023x over previous
//
#include <hip/hip_runtime.h>
#include <hip/hip_bf16.h>

// B=2048, N=512, D=8192.
// Pipeline (NO d_ws use — round-6 d_ws-resident partials caused replay divergence
// on assign; all scratch lives in d_out with per-block ownership):
//   1. m_norms:     mm[n]=||m_n||^2 -> p-slot (dead after rescore)
//   2. gemm_coarse: bf16 MFMA dot partials, splitK=8 -> m+sd regions (32 MB, dead
//                   after rescore). 64x128 tiles -> 1024 blocks = 4/CU (occupancy
//                   is the proven lever: 1->2 blocks/CU gave 106->68 us).
//   3. rescore:     coarse argmin + margin candidates; exact f32 dots only if >=2
//                   cands. Bit-identical assign math to round 5 (passed post-timing).
//   4. build_lists: per-cluster ordered item lists, 4 copies (one per D-slice) into
//                   m-row slice heads; counts into sd-row slice heads
//   5. ema_scatter: grid (N,4); block (n,s) owns 2048-float slice s of cluster n;
//                   8x batched y-loads, exact-order EMA application.

#define Bb 2048
#define Nn 512
#define Dd 8192
#define MARGIN 12.0f
#define KC 8
#define KSTEPS 32   // (Dd/KC)/32

typedef __attribute__((ext_vector_type(4))) float f32x4;
typedef __attribute__((ext_vector_type(8))) short s16x8;

union Frag { unsigned u[4]; s16x8 s; };

__device__ inline unsigned pack2(float lo, float hi) {
    return __builtin_amdgcn_perm(__float_as_uint(hi), __float_as_uint(lo), 0x07060302u);
}

__device__ inline void ema4(float4& mcv, float4& scv, const float4 yv) {
#define EMA_C(c) { mcv.c = mcv.c * 0.001f + yv.c * 0.999f; \
                   float d_ = mcv.c - yv.c;                 \
                   scv.c = d_ * d_ * 0.001f + scv.c * 0.999f; }
    EMA_C(x) EMA_C(y) EMA_C(z) EMA_C(w)
#undef EMA_C
}

// ---------------- 1: m row norms ----------------
__global__ __launch_bounds__(256) void m_norms(const float* __restrict__ M,
                                               float* __restrict__ mm) {
    int n = blockIdx.x, t = threadIdx.x;
    const float4* r = (const float4*)(M + (size_t)n * Dd);
    float s = 0.f;
#pragma unroll
    for (int u = 0; u < 8; u++) {
        float4 v = r[t + 256 * u];
        s += v.x * v.x + v.y * v.y + v.z * v.z + v.w * v.w;
    }
    __shared__ float red[256];
    red[t] = s;
    __syncthreads();
    for (int off = 128; off > 0; off >>= 1) {
        if (t < off) red[t] += red[t + off];
        __syncthreads();
    }
    if (t == 0) mm[n] = red[0];
}

// ---------------- 2: coarse bf16 MFMA GEMM (dot only), splitK=8 ----------------
// grid (4 coltiles, 32 rowtiles, 8 kchunks) = 1024 blocks (4/CU), 256 threads.
// Tile 64x128, K-chunk 1024 (32 steps of 32). f32 staged via global_load_lds
// with XOR seg-swizzle; converted to bf16 at fragment read. Wave w owns cols
// w*32..w*32+31 across all 64 rows.
__global__ __launch_bounds__(256) void gemm_coarse(const float* __restrict__ Y,
                                                   const float* __restrict__ M,
                                                   float* __restrict__ part) {
    __shared__ __align__(16) float As[64 * 32];    // 8 KB
    __shared__ __align__(16) float Bs[128 * 32];   // 16 KB
    const int t = threadIdx.x;
    const int lane = t & 63;
    const int w = t >> 6;
    const int ct = blockIdx.x, rt = blockIdx.y, kc = blockIdx.z;

    const size_t ybase = (size_t)rt * 64 * Dd + (size_t)kc * (KSTEPS * 32);
    const size_t mbase = (size_t)ct * 128 * Dd + (size_t)kc * (KSTEPS * 32);

    // A staging: wave w, u in 0..1 -> flat = (w*2+u)*64 + lane  (covers 64 rows x 8 segs)
    int rowA[2], soffA[2];
#pragma unroll
    for (int u = 0; u < 2; u++) {
        int flat = (w * 2 + u) * 64 + lane;
        int row = flat >> 3, seg = flat & 7;
        rowA[u] = row;
        soffA[u] = (seg ^ (row & 7)) * 4;
    }
    // B staging: wave w, u in 0..3 -> flat = (w*4+u)*64 + lane  (128 rows x 8 segs)
    int rowB[4], soffB[4];
#pragma unroll
    for (int u = 0; u < 4; u++) {
        int flat = (w * 4 + u) * 64 + lane;
        int row = flat >> 3, seg = flat & 7;
        rowB[u] = row;
        soffB[u] = (seg ^ (row & 7)) * 4;
    }

    const int wc0 = w * 32;
    const int l15 = lane & 15, quad = lane >> 4;

    f32x4 acc[4][2];
#pragma unroll
    for (int i = 0; i < 4; i++)
#pragma unroll
        for (int j = 0; j < 2; j++) acc[i][j] = (f32x4)(0.0f);

    for (int step = 0; step < KSTEPS; step++) {
        const int kpos = step * 32;
#pragma unroll
        for (int u = 0; u < 2; u++) {
            const float* gA = Y + ybase + (size_t)rowA[u] * Dd + kpos + soffA[u];
            __builtin_amdgcn_global_load_lds(
                (const __attribute__((address_space(1))) void*)gA,
                (__attribute__((address_space(3))) void*)(As + (w * 2 + u) * 256), 16, 0, 0);
        }
#pragma unroll
        for (int u = 0; u < 4; u++) {
            const float* gB = M + mbase + (size_t)rowB[u] * Dd + kpos + soffB[u];
            __builtin_amdgcn_global_load_lds(
                (const __attribute__((address_space(1))) void*)gB,
                (__attribute__((address_space(3))) void*)(Bs + (w * 4 + u) * 256), 16, 0, 0);
        }
        __syncthreads();

        Frag fa[4], fb[2];
#pragma unroll
        for (int ta = 0; ta < 4; ta++) {
            int rowa = ta * 16 + l15;
            const float* Ar = As + rowa * 32;
            int s0 = ((quad * 2) ^ (rowa & 7)) * 4;
            int s1 = ((quad * 2 + 1) ^ (rowa & 7)) * 4;
            f32x4 x0 = *(const f32x4*)(Ar + s0);
            f32x4 x1 = *(const f32x4*)(Ar + s1);
            fa[ta].u[0] = pack2(x0[0], x0[1]);
            fa[ta].u[1] = pack2(x0[2], x0[3]);
            fa[ta].u[2] = pack2(x1[0], x1[1]);
            fa[ta].u[3] = pack2(x1[2], x1[3]);
        }
#pragma unroll
        for (int tb = 0; tb < 2; tb++) {
            int rowb = wc0 + tb * 16 + l15;
            const float* Br = Bs + rowb * 32;
            int s0 = ((quad * 2) ^ (rowb & 7)) * 4;
            int s1 = ((quad * 2 + 1) ^ (rowb & 7)) * 4;
            f32x4 x0 = *(const f32x4*)(Br + s0);
            f32x4 x1 = *(const f32x4*)(Br + s1);
            fb[tb].u[0] = pack2(x0[0], x0[1]);
            fb[tb].u[1] = pack2(x0[2], x0[3]);
            fb[tb].u[2] = pack2(x1[0], x1[1]);
            fb[tb].u[3] = pack2(x1[2], x1[3]);
        }
#pragma unroll
        for (int i = 0; i < 4; i++)
#pragma unroll
            for (int j = 0; j < 2; j++)
                acc[i][j] = __builtin_amdgcn_mfma_f32_16x16x32_bf16(fa[i].s, fb[j].s, acc[i][j], 0, 0, 0);
        __syncthreads();
    }

    // store partials; C/D layout: col = lane&15, row = quad*4 + reg
    float* P = part + (size_t)kc * (Bb * Nn);
#pragma unroll
    for (int i = 0; i < 4; i++) {
        int rg = rt * 64 + i * 16 + quad * 4;
#pragma unroll
        for (int j = 0; j < 2; j++) {
            int cg = ct * 128 + wc0 + j * 16 + l15;
#pragma unroll
            for (int r = 0; r < 4; r++)
                P[(size_t)(rg + r) * Nn + cg] = acc[i][j][r];
        }
    }
}

// ---------------- 3: coarse argmin + conditional exact rescore ----------------
__global__ __launch_bounds__(256) void rescore(const float* __restrict__ Y,
                                               const float* __restrict__ M,
                                               const float* __restrict__ part,
                                               const float* __restrict__ mm,
                                               float* __restrict__ assignF) {
    __shared__ float redW[4];
    __shared__ int candList[Nn];
    __shared__ int candCnt;
    int b = blockIdx.x, t = threadIdx.x, lane = t & 63, w = t >> 6;
    if (t == 0) candCnt = 0;

    int c0 = t, c1 = t + 256;
    float dot0 = 0.f, dot1 = 0.f;
#pragma unroll
    for (int k = 0; k < KC; k++) {
        dot0 += part[(size_t)k * (Bb * Nn) + (size_t)b * Nn + c0];
        dot1 += part[(size_t)k * (Bb * Nn) + (size_t)b * Nn + c1];
    }
    float d0 = mm[c0] - 2.0f * dot0;
    float d1 = mm[c1] - 2.0f * dot1;

    float mn = fminf(d0, d1);
#pragma unroll
    for (int off = 32; off > 0; off >>= 1) mn = fminf(mn, __shfl_xor(mn, off));
    if (lane == 0) redW[w] = mn;
    __syncthreads();
    float thresh = fminf(fminf(redW[0], redW[1]), fminf(redW[2], redW[3])) + MARGIN;

    if (d0 <= thresh) candList[atomicAdd(&candCnt, 1)] = c0;
    if (d1 <= thresh) candList[atomicAdd(&candCnt, 1)] = c1;
    __syncthreads();
    int ncand = candCnt;

    if (ncand == 1) {                 // uncontested coarse winner: exact dot unnecessary
        if (t == 0) assignF[b] = (float)candList[0];
        return;
    }

    float bestV = 3.4e38f;
    int bestI = 0x3fffffff;
    for (int j = 0; j < ncand; j++) {
        int c = candList[j];
        const float4* yr = (const float4*)(Y + (size_t)b * Dd);
        const float4* mr = (const float4*)(M + (size_t)c * Dd);
        float p = 0.f;
#pragma unroll
        for (int u = 0; u < 8; u++) {
            float4 yv = yr[t + 256 * u];
            float4 mv = mr[t + 256 * u];
            p += yv.x * mv.x + yv.y * mv.y + yv.z * mv.z + yv.w * mv.w;
        }
#pragma unroll
        for (int off = 32; off > 0; off >>= 1) p += __shfl_xor(p, off);
        if (lane == 0) redW[w] = p;
        __syncthreads();
        if (t == 0) {
            float d2e = mm[c] - 2.0f * (redW[0] + redW[1] + redW[2] + redW[3]);
            if (d2e < bestV || (d2e == bestV && c < bestI)) { bestV = d2e; bestI = c; }
        }
        __syncthreads();
    }
    if (t == 0) assignF[b] = (float)bestI;
}

// ---------------- 4: per-cluster ordered lists, 4 slice copies ----------------
__global__ __launch_bounds__(64) void build_lists(const float* __restrict__ assignF,
                                                  float* m_out, float* sd_out) {
    int n = blockIdx.x, lane = threadIdx.x;
    int z[32];
#pragma unroll
    for (int u = 0; u < 32; u++) z[u] = (int)assignF[u * 64 + lane];
    int* lrow = (int*)(m_out + (size_t)n * Dd);
    int cnt = 0;
#pragma unroll
    for (int u = 0; u < 32; u++) {
        unsigned long long mask = __ballot(z[u] == n);
        if (z[u] == n) {
            int pos = cnt + (int)__popcll(mask & ((1ull << lane) - 1ull));
#pragma unroll
            for (int s = 0; s < 4; s++) lrow[s * 2048 + pos] = u * 64 + lane;
        }
        cnt += (int)__popcll(mask);
    }
    if (lane == 0) {
        int* crow = (int*)(sd_out + (size_t)n * Dd);
#pragma unroll
        for (int s = 0; s < 4; s++) crow[s * 2048] = cnt;
    }
}

// ---------------- 5: per-cluster sequential EMA, D-sliced x4, 8x load batch ----
__global__ __launch_bounds__(256) void ema_scatter(const float* __restrict__ Y,
                                                   const float* __restrict__ M0,
                                                   const float* __restrict__ SD0,
                                                   const float* __restrict__ P0,
                                                   float* m_out, float* sd_out, float* p_out) {
    __shared__ int lst[Bb];
    __shared__ int cntSh;
    int n = blockIdx.x, s = blockIdx.y, t = threadIdx.x;
    size_t off = (size_t)n * Dd + (size_t)s * 2048;

    if (t == 0) cntSh = ((const int*)(sd_out + off))[0];
    __syncthreads();
    int cnt = cntSh;
    const int* lsrc = (const int*)(m_out + off);
    for (int u = t; u < cnt; u += 256) lst[u] = lsrc[u];
    __syncthreads();

    float4 mc0 = *(const float4*)(M0 + off + 4 * t);
    float4 mc1 = *(const float4*)(M0 + off + 1024 + 4 * t);
    float4 sc0 = *(const float4*)(SD0 + off + 4 * t);
    float4 sc1 = *(const float4*)(SD0 + off + 1024 + 4 * t);

    // 8x batched loads (independent of the FP chain), then exact-order EMA steps.
    int j = 0;
    for (; j + 8 <= cnt; j += 8) {
        float4 y0[8], y1[8];
#pragma unroll
        for (int q = 0; q < 8; q++) {
            const float* yb = Y + (size_t)lst[j + q] * Dd + (size_t)s * 2048;
            y0[q] = *(const float4*)(yb + 4 * t);
            y1[q] = *(const float4*)(yb + 1024 + 4 * t);
        }
#pragma unroll
        for (int q = 0; q < 8; q++) { ema4(mc0, sc0, y0[q]); ema4(mc1, sc1, y1[q]); }
    }
    for (; j < cnt; j++) {
        const float* yb = Y + (size_t)lst[j] * Dd + (size_t)s * 2048;
        float4 y0 = *(const float4*)(yb + 4 * t);
        float4 y1 = *(const float4*)(yb + 1024 + 4 * t);
        ema4(mc0, sc0, y0);
        ema4(mc1, sc1, y1);
    }

    *(float4*)(m_out + off + 4 * t) = mc0;
    *(float4*)(m_out + off + 1024 + 4 * t) = mc1;
    *(float4*)(sd_out + off + 4 * t) = sc0;
    *(float4*)(sd_out + off + 1024 + 4 * t) = sc1;
    if (s == 0 && t == 0) p_out[n] = P0[n] + (float)cnt;
}

extern "C" void kernel_launch(void* const* d_in, const int* in_sizes, int n_in,
                              void* d_out, int out_size, void* d_ws, size_t ws_size,
                              hipStream_t stream) {
    const float* y  = (const float*)d_in[0];
    const float* m  = (const float*)d_in[1];
    const float* sd = (const float*)d_in[2];
    const float* p  = (const float*)d_in[3];

    float* out     = (float*)d_out;
    float* m_out   = out;                       // also: partials k=0..3, list copies
    float* sd_out  = out + 4194304;             // also: partials k=4..7, count copies
    float* p_out   = out + 8388608;             // also: mm norms
    float* assignF = out + 8389120;

    m_norms    <<<Nn, 256, 0, stream>>>(m, p_out);
    gemm_coarse<<<dim3(4, 32, KC), 256, 0, stream>>>(y, m, m_out);
    rescore    <<<Bb, 256, 0, stream>>>(y, m, m_out, p_out, assignF);
    build_lists<<<Nn, 64, 0, stream>>>(assignF, m_out, sd_out);
    ema_scatter<<<dim3(Nn, 4), 256, 0, stream>>>(y, m, sd, p, m_out, sd_out, p_out);
}